// Round 9
// baseline (226.674 us; speedup 1.0000x reference)
//
#include <hip/hip_runtime.h>
#include <hip/hip_bf16.h>
#include <math.h>

typedef __attribute__((ext_vector_type(8))) short short8;
typedef __attribute__((ext_vector_type(4))) float f32x4;

#define B_    2
#define T_    128
#define D_    256
#define H_    8
#define F_    64
#define C_    512
#define TEMB_ 512
#define HTF_  65536
#define HTT_  131072

static __device__ __forceinline__ unsigned short f2bf(float f) {
  __hip_bfloat16 h = __float2bfloat16(f);
  return reinterpret_cast<unsigned short&>(h);
}
static __device__ __forceinline__ unsigned int pk2(float a, float b) {
  return (unsigned int)f2bf(a) | ((unsigned int)f2bf(b) << 16);
}

// async 16B global->LDS DMA; LDS dest = wave-uniform base + lane*16
static __device__ __forceinline__ void dma16(const void* g, void* l) {
  __builtin_amdgcn_global_load_lds(
      (const __attribute__((address_space(1))) unsigned int*)g,
      (__attribute__((address_space(3))) unsigned int*)l, 16, 0, 0);
}

// ---------------------------------------------------------------------------
// k_pre: merged prep + base (verified R6-R8).
// ---------------------------------------------------------------------------
__global__ __launch_bounds__(256) void k_pre(
    const float* __restrict__ temb, const float* __restrict__ w_time,
    const float* __restrict__ b_time, const float* __restrict__ b_dist,
    const float* __restrict__ w_out, const float* __restrict__ w_dist,
    float* __restrict__ base, short* __restrict__ wsw, float* __restrict__ wdT)
{
  const int tid = threadIdx.x;
  if (blockIdx.x >= 64) {
    int gid = (blockIdx.x - 64) * 256 + tid;
    for (int s = gid; s < 32768; s += 16384) {
      int oi = s >> 10, rem = s & 1023, kjg = rem >> 6, l = rem & 63;
      int o = oi * 16 + (l & 15), c = kjg * 32 + (l >> 4) * 8;
      const float* src = w_out + (size_t)o * C_ + c;
      float4 a = *reinterpret_cast<const float4*>(src);
      float4 b = *reinterpret_cast<const float4*>(src + 4);
      uint4 v; v.x = pk2(a.x, a.y); v.y = pk2(a.z, a.w);
      v.z = pk2(b.x, b.y); v.w = pk2(b.z, b.w);
      *reinterpret_cast<uint4*>(wsw + (size_t)s * 8) = v;
    }
    if (gid < C_) {
      wdT[0 * C_ + gid] = w_dist[gid * 3 + 0];
      wdT[1 * C_ + gid] = w_dist[gid * 3 + 1];
      wdT[2 * C_ + gid] = w_dist[gid * 3 + 2];
    }
    return;
  }
  __shared__ float tt[32][64];
  __shared__ float wt[64][65];
  const int bt0 = (blockIdx.x & 7) * 32;
  const int c0  = (blockIdx.x >> 3) * 64;
  const int cl  = tid & 63;
  const int g   = tid >> 6;
  float acc[8] = {0.f,0.f,0.f,0.f,0.f,0.f,0.f,0.f};

  for (int k0 = 0; k0 < TEMB_; k0 += 64) {
#pragma unroll
    for (int i = 0; i < 8; ++i) {
      int idx = tid + i * 256; int r = idx >> 6, k = idx & 63;
      tt[r][k] = temb[(size_t)(bt0 + r) * TEMB_ + k0 + k];
    }
#pragma unroll
    for (int i = 0; i < 16; ++i) {
      int idx = tid + i * 256; int r = idx >> 6, k = idx & 63;
      wt[r][k] = w_time[(size_t)(c0 + r) * TEMB_ + k0 + k];
    }
    __syncthreads();
#pragma unroll
    for (int k = 0; k < 64; ++k) {
      float w = wt[cl][k];
#pragma unroll
      for (int j = 0; j < 8; ++j) acc[j] += tt[g + 4 * j][k] * w;
    }
    __syncthreads();
  }
  float bb = b_time[c0 + cl] + b_dist[c0 + cl];
#pragma unroll
  for (int j = 0; j < 8; ++j)
    base[(size_t)(bt0 + g + 4 * j) * C_ + c0 + cl] = acc[j] + bb;
}

// ---------------------------------------------------------------------------
// k_rpe: block = (bt, o-half), 512 threads.  R[s][o] -> Rg bf16 (verified R6).
// ---------------------------------------------------------------------------
__global__ __launch_bounds__(512, 4) void k_rpe(
    const float* __restrict__ pd, const float* __restrict__ base,
    const float* __restrict__ wdT, const short* __restrict__ wsw,
    const float* __restrict__ b_out, unsigned short* __restrict__ Rg)
{
  __shared__ __align__(16) short At[8192];
  __shared__ float df[3][T_];

  const int bx   = blockIdx.x;
  const int bt   = bx >> 1;
  const int half = bx & 1;
  const int b    = bt >> 7;
  const int t    = bt & 127;
  const int tid  = threadIdx.x;
  const int lane = tid & 63;
  const int wave = tid >> 6;
  const int lanem = lane & 15;
  const int laneg = lane >> 4;

  if (tid < T_) {
    float p = pd[((size_t)b * T_ + t) * T_ + tid];
    df[0][tid] = log1pf(fmaxf(p, 0.f));
    df[1][tid] = log1pf(fmaxf(-p, 0.f));
    df[2][tid] = (p == 0.f) ? 1.f : 0.f;
  }

  const int wm = wave >> 2;
  const int wn = wave & 3;
  const int s_low = tid & 15;
  const int cg    = (tid >> 4) & 7;
  const int si_b  = (tid >> 7) * 2;
  const int kjA   = cg >> 2;
  const int cgl   = cg & 3;
  const int laneslotA = s_low + 16 * cgl;
  const float* baserow = base + (size_t)bt * C_;

  f32x4 acc[4][4];
#pragma unroll
  for (int mi = 0; mi < 4; ++mi)
#pragma unroll
    for (int ni = 0; ni < 4; ++ni) acc[mi][ni] = (f32x4){0.f, 0.f, 0.f, 0.f};

  for (int kt = 0; kt < 8; ++kt) {
    __syncthreads();
    short8 b0[4], b1[4];
#pragma unroll
    for (int ni = 0; ni < 4; ++ni) {
      int oi = half * 16 + wn * 4 + ni;
      b0[ni] = *reinterpret_cast<const short8*>(
          wsw + ((size_t)(oi * 16 + kt * 2 + 0) * 64 + lane) * 8);
    }
    {
      const int cglob = kt * 64 + cg * 8;
      float4 bs0 = *reinterpret_cast<const float4*>(baserow + cglob);
      float4 bs1 = *reinterpret_cast<const float4*>(baserow + cglob + 4);
      float4 wa0 = *reinterpret_cast<const float4*>(wdT + cglob);
      float4 wa1 = *reinterpret_cast<const float4*>(wdT + cglob + 4);
      float4 wb0 = *reinterpret_cast<const float4*>(wdT + C_ + cglob);
      float4 wb1 = *reinterpret_cast<const float4*>(wdT + C_ + cglob + 4);
      float4 wc0 = *reinterpret_cast<const float4*>(wdT + 2 * C_ + cglob);
      float4 wc1 = *reinterpret_cast<const float4*>(wdT + 2 * C_ + cglob + 4);
#pragma unroll
      for (int q = 0; q < 2; ++q) {
        int si = si_b + q;
        int s  = si * 16 + s_low;
        float d0 = df[0][s], d1 = df[1][s], d2 = df[2][s];
        uint4 v;
        {
          float x0 = bs0.x + d0 * wa0.x + d1 * wb0.x + d2 * wc0.x;
          float x1 = bs0.y + d0 * wa0.y + d1 * wb0.y + d2 * wc0.y;
          float x2 = bs0.z + d0 * wa0.z + d1 * wb0.z + d2 * wc0.z;
          float x3 = bs0.w + d0 * wa0.w + d1 * wb0.w + d2 * wc0.w;
          x0 = x0 / (1.f + __expf(-x0)); x1 = x1 / (1.f + __expf(-x1));
          x2 = x2 / (1.f + __expf(-x2)); x3 = x3 / (1.f + __expf(-x3));
          v.x = pk2(x0, x1); v.y = pk2(x2, x3);
        }
        {
          float x0 = bs1.x + d0 * wa1.x + d1 * wb1.x + d2 * wc1.x;
          float x1 = bs1.y + d0 * wa1.y + d1 * wb1.y + d2 * wc1.y;
          float x2 = bs1.z + d0 * wa1.z + d1 * wb1.z + d2 * wc1.z;
          float x3 = bs1.w + d0 * wa1.w + d1 * wb1.w + d2 * wc1.w;
          x0 = x0 / (1.f + __expf(-x0)); x1 = x1 / (1.f + __expf(-x1));
          x2 = x2 / (1.f + __expf(-x2)); x3 = x3 / (1.f + __expf(-x3));
          v.z = pk2(x0, x1); v.w = pk2(x2, x3);
        }
        *reinterpret_cast<uint4*>(&At[((si * 2 + kjA) * 64 + laneslotA) * 8]) = v;
      }
    }
#pragma unroll
    for (int ni = 0; ni < 4; ++ni) {
      int oi = half * 16 + wn * 4 + ni;
      b1[ni] = *reinterpret_cast<const short8*>(
          wsw + ((size_t)(oi * 16 + kt * 2 + 1) * 64 + lane) * 8);
    }
    __syncthreads();
    {
      short8 a[4];
#pragma unroll
      for (int mi = 0; mi < 4; ++mi)
        a[mi] = *reinterpret_cast<const short8*>(
            &At[(((wm * 4 + mi) * 2 + 0) * 64 + lane) * 8]);
#pragma unroll
      for (int ni = 0; ni < 4; ++ni)
#pragma unroll
        for (int mi = 0; mi < 4; ++mi)
          acc[mi][ni] = __builtin_amdgcn_mfma_f32_16x16x32_bf16(
              b0[ni], a[mi], acc[mi][ni], 0, 0, 0);
#pragma unroll
      for (int mi = 0; mi < 4; ++mi)
        a[mi] = *reinterpret_cast<const short8*>(
            &At[(((wm * 4 + mi) * 2 + 1) * 64 + lane) * 8]);
#pragma unroll
      for (int ni = 0; ni < 4; ++ni)
#pragma unroll
        for (int mi = 0; mi < 4; ++mi)
          acc[mi][ni] = __builtin_amdgcn_mfma_f32_16x16x32_bf16(
              b1[ni], a[mi], acc[mi][ni], 0, 0, 0);
    }
  }

  unsigned short* Rbt = Rg + (size_t)bt * T_ * C_;
#pragma unroll
  for (int ni = 0; ni < 4; ++ni) {
    const int o0 = half * 256 + wn * 64 + ni * 16 + laneg * 4;
    const float4 bo4 = *reinterpret_cast<const float4*>(b_out + o0);
#pragma unroll
    for (int mi = 0; mi < 4; ++mi) {
      const int s = wm * 64 + mi * 16 + lanem;
      uint2 v;
      v.x = pk2(acc[mi][ni][0] + bo4.x, acc[mi][ni][1] + bo4.y);
      v.y = pk2(acc[mi][ni][2] + bo4.z, acc[mi][ni][3] + bo4.w);
      *reinterpret_cast<uint2*>(Rbt + (size_t)s * C_ + o0) = v;
    }
  }
}

// ---------------------------------------------------------------------------
// k_qkr (R7 streaming shape + R8 DMA discipline):
// block = (b,h,tq,dg): bx = dg*64 + grp so bx%8 is constant across the 16
// dg-blocks sharing an R slice (XCD L2 dedupe of the 16x R amplification).
// Per block: 16 d x 32 t x 128 s.  Per t: R[t] h-slice (16 KB) + qk[t]
// (4 KB) DMA-staged to double-buffered LDS (5 insts/wave/t), counted vmcnt,
// raw s_barrier (no drain).  Waves split s (32 each).  MFMA/store mapping
// identical to R7 (verified): D[row=s][col=d], float4 stores of 4 consec s.
// LDS XOR-swizzle via pre-swizzled global source (m173; verified R8).
// ---------------------------------------------------------------------------
__global__ __launch_bounds__(256, 4) void k_qkr(
    const float* __restrict__ qk, const unsigned short* __restrict__ Rg,
    float* __restrict__ out)
{
  __shared__ __align__(16) char lds[2][20480];   // [buf][R 16KB | qk 4KB]

  const int bx  = blockIdx.x;
  const int grp = bx & 63;          // (b,h,tq) -> fixes XCD
  const int dg  = bx >> 6;          // 0..15
  const int b   = grp >> 5;
  const int h   = (grp >> 2) & 7;
  const int tq  = grp & 3;
  const int tid = threadIdx.x;
  const int lane = tid & 63;
  const int wave = tid >> 6;
  const int lanem = lane & 15;
  const int laneg = lane >> 4;

  const int t0 = tq * 32;
  const int d0 = dg * 16;

  const float* qkbase = qk + (size_t)b * D_ * HTF_ + (size_t)d0 * HTF_
                           + (size_t)h * (T_ * F_);
  const unsigned short* Rbase = Rg + (size_t)b * (T_ * T_ * C_) + (size_t)h * F_;
  float* outbase = out + (size_t)(b * D_ + d0) * HTT_ + (size_t)h * (T_ * T_);

  // ---- per-lane DMA sources (t-invariant parts) ----
  // R: round j: slot=(j*4+wave)*64+lane -> s=slot>>3, g=slot&7, gsrc=g^(s&7)
  const unsigned short* rsrc[4];
  int rdst[4];
#pragma unroll
  for (int j = 0; j < 4; ++j) {
    int slot = (j * 4 + wave) * 64 + lane;
    int s = slot >> 3, g = slot & 7;
    int gsrc = g ^ (s & 7);
    rsrc[j] = Rbase + (size_t)t0 * (T_ * C_) + (size_t)s * C_ + gsrc * 8;
    rdst[j] = (j * 4 + wave) * 1024;
  }
  // qk: slot=tid -> d=slot>>4, g=slot&15, gsrc=g^((d&7)<<1)
  const float* qsrc;
  {
    int d = tid >> 4, g = tid & 15;
    int gsrc = g ^ ((d & 7) << 1);
    qsrc = qkbase + (size_t)d * HTF_ + (size_t)t0 * F_ + gsrc * 4;
  }
  const int qdst = 16384 + wave * 1024;

  // ---- per-lane LDS read offsets (t-invariant) ----
  int raddr[2][2];   // [stile][kj]
#pragma unroll
  for (int stile = 0; stile < 2; ++stile) {
    int s = wave * 32 + stile * 16 + lanem;
#pragma unroll
    for (int kj = 0; kj < 2; ++kj) {
      int gr = (kj * 4 + laneg) ^ (s & 7);
      raddr[stile][kj] = s * 128 + gr * 16;
    }
  }
  int qaddr[2];
#pragma unroll
  for (int kj = 0; kj < 2; ++kj) {
    int gg = (kj * 8 + laneg * 2) ^ ((lanem & 7) << 1);
    qaddr[kj] = 16384 + lanem * 256 + gg * 16;
  }

  auto STAGE = [&](int ti, int bufi) {
#pragma unroll
    for (int j = 0; j < 4; ++j)
      dma16(rsrc[j] + (size_t)ti * (T_ * C_), lds[bufi] + rdst[j]);
    dma16(qsrc + (size_t)ti * F_, lds[bufi] + qdst);
  };

  STAGE(0, 0);
  STAGE(1, 1);
  __builtin_amdgcn_sched_barrier(0);

  for (int ti = 0; ti < 32; ++ti) {
    const int bufi = ti & 1;
    // counted waits: FIFO = STAGE(ti),stores(ti-2),STAGE(ti+1),stores(ti-1)
    if (ti == 0)       asm volatile("s_waitcnt vmcnt(5)" ::: "memory");
    else if (ti == 1)  asm volatile("s_waitcnt vmcnt(7)" ::: "memory");
    else if (ti == 31) asm volatile("s_waitcnt vmcnt(4)" ::: "memory");
    else               asm volatile("s_waitcnt vmcnt(9)" ::: "memory");
    __builtin_amdgcn_sched_barrier(0);
    __builtin_amdgcn_s_barrier();          // all waves' STAGE(ti) landed
    __builtin_amdgcn_sched_barrier(0);

    const char* bufp = lds[bufi];
    short8 av[2][2];                       // [kj][stile]
    float4 qf[2][2];
#pragma unroll
    for (int stile = 0; stile < 2; ++stile)
#pragma unroll
      for (int kj = 0; kj < 2; ++kj)
        av[kj][stile] = *reinterpret_cast<const short8*>(bufp + raddr[stile][kj]);
#pragma unroll
    for (int kj = 0; kj < 2; ++kj) {
      qf[kj][0] = *reinterpret_cast<const float4*>(bufp + qaddr[kj]);
      qf[kj][1] = *reinterpret_cast<const float4*>(bufp + qaddr[kj] + 16);
    }
    asm volatile("s_waitcnt lgkmcnt(0)" ::: "memory");
    __builtin_amdgcn_sched_barrier(0);
    __builtin_amdgcn_s_barrier();          // all waves done reading buf
    __builtin_amdgcn_sched_barrier(0);
    if (ti < 30) STAGE(ti + 2, bufi);      // refill freed buffer

    short8 qb[2];
#pragma unroll
    for (int kj = 0; kj < 2; ++kj) {
      union { uint4 u; short8 s; } cv;
      cv.u.x = pk2(qf[kj][0].x, qf[kj][0].y);
      cv.u.y = pk2(qf[kj][0].z, qf[kj][0].w);
      cv.u.z = pk2(qf[kj][1].x, qf[kj][1].y);
      cv.u.w = pk2(qf[kj][1].z, qf[kj][1].w);
      qb[kj] = cv.s;
    }
    f32x4 ac[2];
    ac[0] = (f32x4){0.f, 0.f, 0.f, 0.f};
    ac[1] = (f32x4){0.f, 0.f, 0.f, 0.f};
#pragma unroll
    for (int kj = 0; kj < 2; ++kj)
#pragma unroll
      for (int stile = 0; stile < 2; ++stile)
        ac[stile] = __builtin_amdgcn_mfma_f32_16x16x32_bf16(
            av[kj][stile], qb[kj], ac[stile], 0, 0, 0);

    const int t = t0 + ti;
    float* od = outbase + (size_t)lanem * HTT_ + (size_t)t * T_
                        + wave * 32 + laneg * 4;
    *reinterpret_cast<float4*>(od)      = (float4){ac[0][0], ac[0][1], ac[0][2], ac[0][3]};
    *reinterpret_cast<float4*>(od + 16) = (float4){ac[1][0], ac[1][1], ac[1][2], ac[1][3]};
  }
}

extern "C" void kernel_launch(void* const* d_in, const int* in_sizes, int n_in,
                              void* d_out, int out_size, void* d_ws, size_t ws_size,
                              hipStream_t stream) {
  const float* qk     = (const float*)d_in[0];
  const float* pd     = (const float*)d_in[1];
  const float* temb   = (const float*)d_in[2];
  const float* w_dist = (const float*)d_in[3];
  const float* b_dist = (const float*)d_in[4];
  const float* w_time = (const float*)d_in[5];
  const float* b_time = (const float*)d_in[6];
  const float* w_out  = (const float*)d_in[7];
  const float* b_out  = (const float*)d_in[8];
  float* out = (float*)d_out;

  char* ws = (char*)d_ws;
  float* base          = (float*)(ws);                    // 524288 B
  float* wdT           = (float*)(ws + 524288);           //   8192 B slot
  short* wsw           = (short*)(ws + 532480);           // 524288 B
  unsigned short* Rg   = (unsigned short*)(ws + 1056768); // 33554432 B

  hipLaunchKernelGGL(k_pre, dim3(128), dim3(256), 0, stream,
                     temb, w_time, b_time, b_dist, w_out, w_dist,
                     base, wsw, wdT);
  hipLaunchKernelGGL(k_rpe, dim3(2 * B_ * T_), dim3(512), 0, stream,
                     pd, base, wdT, wsw, b_out, Rg);
  hipLaunchKernelGGL(k_qkr, dim3(1024), dim3(256), 0, stream,
                     qk, Rg, out);
}

// Round 10
// 226.068 us; speedup vs baseline: 1.0027x; 1.0027x over previous
//
#include <hip/hip_runtime.h>
#include <hip/hip_bf16.h>
#include <math.h>

typedef __attribute__((ext_vector_type(8))) short short8;
typedef __attribute__((ext_vector_type(4))) float f32x4;

#define B_    2
#define T_    128
#define D_    256
#define H_    8
#define F_    64
#define C_    512
#define TEMB_ 512
#define HTF_  65536
#define HTT_  131072

static __device__ __forceinline__ unsigned short f2bf(float f) {
  __hip_bfloat16 h = __float2bfloat16(f);
  return reinterpret_cast<unsigned short&>(h);
}
static __device__ __forceinline__ unsigned int pk2(float a, float b) {
  return (unsigned int)f2bf(a) | ((unsigned int)f2bf(b) << 16);
}

// async 16B global->LDS DMA; LDS dest = wave-uniform base + lane*16
static __device__ __forceinline__ void dma16(const void* g, void* l) {
  __builtin_amdgcn_global_load_lds(
      (const __attribute__((address_space(1))) unsigned int*)g,
      (__attribute__((address_space(3))) unsigned int*)l, 16, 0, 0);
}

// ---------------------------------------------------------------------------
// k_pre: merged prep + base (verified R6-R9).
// ---------------------------------------------------------------------------
__global__ __launch_bounds__(256) void k_pre(
    const float* __restrict__ temb, const float* __restrict__ w_time,
    const float* __restrict__ b_time, const float* __restrict__ b_dist,
    const float* __restrict__ w_out, const float* __restrict__ w_dist,
    float* __restrict__ base, short* __restrict__ wsw, float* __restrict__ wdT)
{
  const int tid = threadIdx.x;
  if (blockIdx.x >= 64) {
    int gid = (blockIdx.x - 64) * 256 + tid;
    for (int s = gid; s < 32768; s += 16384) {
      int oi = s >> 10, rem = s & 1023, kjg = rem >> 6, l = rem & 63;
      int o = oi * 16 + (l & 15), c = kjg * 32 + (l >> 4) * 8;
      const float* src = w_out + (size_t)o * C_ + c;
      float4 a = *reinterpret_cast<const float4*>(src);
      float4 b = *reinterpret_cast<const float4*>(src + 4);
      uint4 v; v.x = pk2(a.x, a.y); v.y = pk2(a.z, a.w);
      v.z = pk2(b.x, b.y); v.w = pk2(b.z, b.w);
      *reinterpret_cast<uint4*>(wsw + (size_t)s * 8) = v;
    }
    if (gid < C_) {
      wdT[0 * C_ + gid] = w_dist[gid * 3 + 0];
      wdT[1 * C_ + gid] = w_dist[gid * 3 + 1];
      wdT[2 * C_ + gid] = w_dist[gid * 3 + 2];
    }
    return;
  }
  __shared__ float tt[32][64];
  __shared__ float wt[64][65];
  const int bt0 = (blockIdx.x & 7) * 32;
  const int c0  = (blockIdx.x >> 3) * 64;
  const int cl  = tid & 63;
  const int g   = tid >> 6;
  float acc[8] = {0.f,0.f,0.f,0.f,0.f,0.f,0.f,0.f};

  for (int k0 = 0; k0 < TEMB_; k0 += 64) {
#pragma unroll
    for (int i = 0; i < 8; ++i) {
      int idx = tid + i * 256; int r = idx >> 6, k = idx & 63;
      tt[r][k] = temb[(size_t)(bt0 + r) * TEMB_ + k0 + k];
    }
#pragma unroll
    for (int i = 0; i < 16; ++i) {
      int idx = tid + i * 256; int r = idx >> 6, k = idx & 63;
      wt[r][k] = w_time[(size_t)(c0 + r) * TEMB_ + k0 + k];
    }
    __syncthreads();
#pragma unroll
    for (int k = 0; k < 64; ++k) {
      float w = wt[cl][k];
#pragma unroll
      for (int j = 0; j < 8; ++j) acc[j] += tt[g + 4 * j][k] * w;
    }
    __syncthreads();
  }
  float bb = b_time[c0 + cl] + b_dist[c0 + cl];
#pragma unroll
  for (int j = 0; j < 8; ++j)
    base[(size_t)(bt0 + g + 4 * j) * C_ + c0 + cl] = acc[j] + bb;
}

// ---------------------------------------------------------------------------
// k_rpe: block = (bt, o-half), 512 threads (verified R6-R9); epilogue now
// writes R in LINEAR layout Rlin[b][h][t][s][f] (h = half*4+wn, constant
// per wave) so k_qkr's R reads are contiguous.
// ---------------------------------------------------------------------------
__global__ __launch_bounds__(512, 4) void k_rpe(
    const float* __restrict__ pd, const float* __restrict__ base,
    const float* __restrict__ wdT, const short* __restrict__ wsw,
    const float* __restrict__ b_out, unsigned short* __restrict__ Rlin)
{
  __shared__ __align__(16) short At[8192];
  __shared__ float df[3][T_];

  const int bx   = blockIdx.x;
  const int bt   = bx >> 1;
  const int half = bx & 1;
  const int b    = bt >> 7;
  const int t    = bt & 127;
  const int tid  = threadIdx.x;
  const int lane = tid & 63;
  const int wave = tid >> 6;
  const int lanem = lane & 15;
  const int laneg = lane >> 4;

  if (tid < T_) {
    float p = pd[((size_t)b * T_ + t) * T_ + tid];
    df[0][tid] = log1pf(fmaxf(p, 0.f));
    df[1][tid] = log1pf(fmaxf(-p, 0.f));
    df[2][tid] = (p == 0.f) ? 1.f : 0.f;
  }

  const int wm = wave >> 2;
  const int wn = wave & 3;
  const int s_low = tid & 15;
  const int cg    = (tid >> 4) & 7;
  const int si_b  = (tid >> 7) * 2;
  const int kjA   = cg >> 2;
  const int cgl   = cg & 3;
  const int laneslotA = s_low + 16 * cgl;
  const float* baserow = base + (size_t)bt * C_;

  f32x4 acc[4][4];
#pragma unroll
  for (int mi = 0; mi < 4; ++mi)
#pragma unroll
    for (int ni = 0; ni < 4; ++ni) acc[mi][ni] = (f32x4){0.f, 0.f, 0.f, 0.f};

  for (int kt = 0; kt < 8; ++kt) {
    __syncthreads();
    short8 b0[4], b1[4];
#pragma unroll
    for (int ni = 0; ni < 4; ++ni) {
      int oi = half * 16 + wn * 4 + ni;
      b0[ni] = *reinterpret_cast<const short8*>(
          wsw + ((size_t)(oi * 16 + kt * 2 + 0) * 64 + lane) * 8);
    }
    {
      const int cglob = kt * 64 + cg * 8;
      float4 bs0 = *reinterpret_cast<const float4*>(baserow + cglob);
      float4 bs1 = *reinterpret_cast<const float4*>(baserow + cglob + 4);
      float4 wa0 = *reinterpret_cast<const float4*>(wdT + cglob);
      float4 wa1 = *reinterpret_cast<const float4*>(wdT + cglob + 4);
      float4 wb0 = *reinterpret_cast<const float4*>(wdT + C_ + cglob);
      float4 wb1 = *reinterpret_cast<const float4*>(wdT + C_ + cglob + 4);
      float4 wc0 = *reinterpret_cast<const float4*>(wdT + 2 * C_ + cglob);
      float4 wc1 = *reinterpret_cast<const float4*>(wdT + 2 * C_ + cglob + 4);
#pragma unroll
      for (int q = 0; q < 2; ++q) {
        int si = si_b + q;
        int s  = si * 16 + s_low;
        float d0 = df[0][s], d1 = df[1][s], d2 = df[2][s];
        uint4 v;
        {
          float x0 = bs0.x + d0 * wa0.x + d1 * wb0.x + d2 * wc0.x;
          float x1 = bs0.y + d0 * wa0.y + d1 * wb0.y + d2 * wc0.y;
          float x2 = bs0.z + d0 * wa0.z + d1 * wb0.z + d2 * wc0.z;
          float x3 = bs0.w + d0 * wa0.w + d1 * wb0.w + d2 * wc0.w;
          x0 = x0 / (1.f + __expf(-x0)); x1 = x1 / (1.f + __expf(-x1));
          x2 = x2 / (1.f + __expf(-x2)); x3 = x3 / (1.f + __expf(-x3));
          v.x = pk2(x0, x1); v.y = pk2(x2, x3);
        }
        {
          float x0 = bs1.x + d0 * wa1.x + d1 * wb1.x + d2 * wc1.x;
          float x1 = bs1.y + d0 * wa1.y + d1 * wb1.y + d2 * wc1.y;
          float x2 = bs1.z + d0 * wa1.z + d1 * wb1.z + d2 * wc1.z;
          float x3 = bs1.w + d0 * wa1.w + d1 * wb1.w + d2 * wc1.w;
          x0 = x0 / (1.f + __expf(-x0)); x1 = x1 / (1.f + __expf(-x1));
          x2 = x2 / (1.f + __expf(-x2)); x3 = x3 / (1.f + __expf(-x3));
          v.z = pk2(x0, x1); v.w = pk2(x2, x3);
        }
        *reinterpret_cast<uint4*>(&At[((si * 2 + kjA) * 64 + laneslotA) * 8]) = v;
      }
    }
#pragma unroll
    for (int ni = 0; ni < 4; ++ni) {
      int oi = half * 16 + wn * 4 + ni;
      b1[ni] = *reinterpret_cast<const short8*>(
          wsw + ((size_t)(oi * 16 + kt * 2 + 1) * 64 + lane) * 8);
    }
    __syncthreads();
    {
      short8 a[4];
#pragma unroll
      for (int mi = 0; mi < 4; ++mi)
        a[mi] = *reinterpret_cast<const short8*>(
            &At[(((wm * 4 + mi) * 2 + 0) * 64 + lane) * 8]);
#pragma unroll
      for (int ni = 0; ni < 4; ++ni)
#pragma unroll
        for (int mi = 0; mi < 4; ++mi)
          acc[mi][ni] = __builtin_amdgcn_mfma_f32_16x16x32_bf16(
              b0[ni], a[mi], acc[mi][ni], 0, 0, 0);
#pragma unroll
      for (int mi = 0; mi < 4; ++mi)
        a[mi] = *reinterpret_cast<const short8*>(
            &At[(((wm * 4 + mi) * 2 + 1) * 64 + lane) * 8]);
#pragma unroll
      for (int ni = 0; ni < 4; ++ni)
#pragma unroll
        for (int mi = 0; mi < 4; ++mi)
          acc[mi][ni] = __builtin_amdgcn_mfma_f32_16x16x32_bf16(
              b1[ni], a[mi], acc[mi][ni], 0, 0, 0);
    }
  }

  // epilogue -> Rlin[b][h][t][s][f]; h = half*4 + wn (wave-constant)
  const int h = half * 4 + wn;
  unsigned short* Rh = Rlin + (((size_t)(b * H_ + h) * T_ + t) * T_) * F_;
#pragma unroll
  for (int ni = 0; ni < 4; ++ni) {
    const int f0 = ni * 16 + laneg * 4;
    const float4 bo4 = *reinterpret_cast<const float4*>(b_out + h * 64 + f0);
#pragma unroll
    for (int mi = 0; mi < 4; ++mi) {
      const int s = wm * 64 + mi * 16 + lanem;
      uint2 v;
      v.x = pk2(acc[mi][ni][0] + bo4.x, acc[mi][ni][1] + bo4.y);
      v.y = pk2(acc[mi][ni][2] + bo4.z, acc[mi][ni][3] + bo4.w);
      *reinterpret_cast<uint2*>(Rh + (size_t)s * F_ + f0) = v;
    }
  }
}

// ---------------------------------------------------------------------------
// k_qkr: streaming + barrier-FREE.  bx = dg*64 + grp, grp=(b,h,tq) so the 16
// dg-blocks sharing an R slice stay on one XCD.  Block = 16d x 32t x 128s;
// each wave owns 16d x 32s x 32t with PRIVATE double-buffered LDS
// (R quarter 4KB contiguous from Rlin + qk 4KB), counted per-wave vmcnt
// (FIFO-derived 8/10/12..12/4), no s_barrier anywhere.
// ---------------------------------------------------------------------------
__global__ __launch_bounds__(256, 4) void k_qkr(
    const float* __restrict__ qk, const unsigned short* __restrict__ Rlin,
    float* __restrict__ out)
{
  __shared__ __align__(16) char lds[4][2][8192];   // [wave][buf][R 4K | qk 4K]

  const int bx  = blockIdx.x;
  const int grp = bx & 63;
  const int dg  = bx >> 6;
  const int b   = grp >> 5;
  const int h   = (grp >> 2) & 7;
  const int tq  = grp & 3;
  const int tid = threadIdx.x;
  const int lane = tid & 63;
  const int wave = tid >> 6;          // = s-quarter wq
  const int lanem = lane & 15;
  const int laneg = lane >> 4;

  const int t0 = tq * 32;
  const int d0 = dg * 16;

  const unsigned short* Rb = Rlin + ((size_t)(b * H_ + h) * T_) * T_ * F_;
  const float* qkbase = qk + (size_t)b * D_ * HTF_ + (size_t)d0 * HTF_
                           + (size_t)h * (T_ * F_);
  float* outbase = out + (size_t)(b * D_ + d0) * HTT_ + (size_t)h * (T_ * T_);

  // ---- per-lane DMA sources (advance per ti) ----
  // R: inst j covers s_rel = j*8+(lane>>3) of wave's quarter; granule swz key s&7
  const unsigned short* rsrc[4];
#pragma unroll
  for (int j = 0; j < 4; ++j) {
    int s_loc = wave * 32 + j * 8 + (lane >> 3);
    int gs = (lane & 7) ^ (s_loc & 7);
    rsrc[j] = Rb + ((size_t)t0 * T_ + s_loc) * F_ + gs * 8;
  }
  // qk: inst j covers d_rel = j*4+(lane>>4); granule swz key (d&7)<<1
  const float* qsrc[4];
#pragma unroll
  for (int j = 0; j < 4; ++j) {
    int d_rel = j * 4 + (lane >> 4);
    int gs = (lane & 15) ^ ((d_rel & 7) << 1);
    qsrc[j] = qkbase + (size_t)d_rel * HTF_ + (size_t)t0 * F_ + gs * 4;
  }

  // ---- per-lane LDS read offsets (within wave's buf region) ----
  int raddr[2][2];   // [stile][kj]: R A-frag, conflict-free (8-bank spread)
#pragma unroll
  for (int stile = 0; stile < 2; ++stile) {
    int s_rel = stile * 16 + lanem;
#pragma unroll
    for (int kj = 0; kj < 2; ++kj)
      raddr[stile][kj] = s_rel * 128 + ((kj * 4 + laneg) ^ (s_rel & 7)) * 16;
  }
  int qaddr[2];      // qk B-frag (2 consecutive granules each)
#pragma unroll
  for (int kj = 0; kj < 2; ++kj)
    qaddr[kj] = 4096 + lanem * 256 + ((kj * 8 + laneg * 2) ^ ((lanem & 7) << 1)) * 16;

  auto STAGE = [&](int ti, int bufi) {
    char* dst = lds[wave][bufi];
#pragma unroll
    for (int j = 0; j < 4; ++j)
      dma16(rsrc[j] + (size_t)ti * (T_ * F_), dst + j * 1024);
#pragma unroll
    for (int j = 0; j < 4; ++j)
      dma16(qsrc[j] + (size_t)ti * F_, dst + 4096 + j * 1024);
  };

  STAGE(0, 0);
  STAGE(1, 1);
  __builtin_amdgcn_sched_barrier(0);

  for (int ti = 0; ti < 32; ++ti) {
    const int bufi = ti & 1;
    // per-wave counted waits (FIFO: STAGE=8 vm-ops, stores=2 vm-ops per iter)
    if (ti == 0)       asm volatile("s_waitcnt vmcnt(8)"  ::: "memory");
    else if (ti == 1)  asm volatile("s_waitcnt vmcnt(10)" ::: "memory");
    else if (ti == 31) asm volatile("s_waitcnt vmcnt(4)"  ::: "memory");
    else               asm volatile("s_waitcnt vmcnt(12)" ::: "memory");
    __builtin_amdgcn_sched_barrier(0);

    const char* bufp = lds[wave][bufi];
    short8 av[2][2];
    float4 qf[2][2];
#pragma unroll
    for (int stile = 0; stile < 2; ++stile)
#pragma unroll
      for (int kj = 0; kj < 2; ++kj)
        av[kj][stile] = *reinterpret_cast<const short8*>(bufp + raddr[stile][kj]);
#pragma unroll
    for (int kj = 0; kj < 2; ++kj) {
      qf[kj][0] = *reinterpret_cast<const float4*>(bufp + qaddr[kj]);
      qf[kj][1] = *reinterpret_cast<const float4*>(bufp + qaddr[kj] + 16);
    }
    asm volatile("s_waitcnt lgkmcnt(0)" ::: "memory");
    __builtin_amdgcn_sched_barrier(0);
    if (ti < 30) STAGE(ti + 2, bufi);      // refill freed private buffer

    short8 qb[2];
#pragma unroll
    for (int kj = 0; kj < 2; ++kj) {
      union { uint4 u; short8 s; } cv;
      cv.u.x = pk2(qf[kj][0].x, qf[kj][0].y);
      cv.u.y = pk2(qf[kj][0].z, qf[kj][0].w);
      cv.u.z = pk2(qf[kj][1].x, qf[kj][1].y);
      cv.u.w = pk2(qf[kj][1].z, qf[kj][1].w);
      qb[kj] = cv.s;
    }
    f32x4 ac[2];
    ac[0] = (f32x4){0.f, 0.f, 0.f, 0.f};
    ac[1] = (f32x4){0.f, 0.f, 0.f, 0.f};
#pragma unroll
    for (int kj = 0; kj < 2; ++kj)
#pragma unroll
      for (int stile = 0; stile < 2; ++stile)
        ac[stile] = __builtin_amdgcn_mfma_f32_16x16x32_bf16(
            av[kj][stile], qb[kj], ac[stile], 0, 0, 0);

    const int t = t0 + ti;
    float* od = outbase + (size_t)lanem * HTT_ + (size_t)t * T_
                        + wave * 32 + laneg * 4;
    *reinterpret_cast<float4*>(od)      = (float4){ac[0][0], ac[0][1], ac[0][2], ac[0][3]};
    *reinterpret_cast<float4*>(od + 16) = (float4){ac[1][0], ac[1][1], ac[1][2], ac[1][3]};
  }
}

extern "C" void kernel_launch(void* const* d_in, const int* in_sizes, int n_in,
                              void* d_out, int out_size, void* d_ws, size_t ws_size,
                              hipStream_t stream) {
  const float* qk     = (const float*)d_in[0];
  const float* pd     = (const float*)d_in[1];
  const float* temb   = (const float*)d_in[2];
  const float* w_dist = (const float*)d_in[3];
  const float* b_dist = (const float*)d_in[4];
  const float* w_time = (const float*)d_in[5];
  const float* b_time = (const float*)d_in[6];
  const float* w_out  = (const float*)d_in[7];
  const float* b_out  = (const float*)d_in[8];
  float* out = (float*)d_out;

  char* ws = (char*)d_ws;
  float* base          = (float*)(ws);                    // 524288 B
  float* wdT           = (float*)(ws + 524288);           //   8192 B slot
  short* wsw           = (short*)(ws + 532480);           // 524288 B
  unsigned short* Rlin = (unsigned short*)(ws + 1056768); // 33554432 B

  hipLaunchKernelGGL(k_pre, dim3(128), dim3(256), 0, stream,
                     temb, w_time, b_time, b_dist, w_out, w_dist,
                     base, wsw, wdT);
  hipLaunchKernelGGL(k_rpe, dim3(2 * B_ * T_), dim3(512), 0, stream,
                     pd, base, wdT, wsw, b_out, Rlin);
  hipLaunchKernelGGL(k_qkr, dim3(1024), dim3(256), 0, stream,
                     qk, Rlin, out);
}